// Round 4
// baseline (462.901 us; speedup 1.0000x reference)
//
#include <hip/hip_runtime.h>
#include <math.h>

#define NN 100000
#define NE 1600000
#define SLOTS 48           // fixed csr stride; P(deg>=48) ~ 6e-11 per node
#define NODES_PER_BUCKET 12500   // 8 buckets x 12500 = NN
#define SEGS 256
#define QUADS (NE / 4)     // 400000
#define QPS ((QUADS + SEGS - 1) / SEGS)  // 1563

// bf16 <-> f32 helpers (bf16 stored as raw ushort; value<<16 == f32 bits)
__device__ __forceinline__ float bf2f(unsigned int u) {
    union { unsigned int u; float f; } c; c.u = u << 16; return c.f;
}
__device__ __forceinline__ unsigned short f2bf(float f) {
    union { float f; unsigned int u; } c; c.f = f;
    unsigned int x = c.u;
    return (unsigned short)((x + 0x7fffu + ((x >> 16) & 1u)) >> 16); // RNE
}

typedef __attribute__((ext_vector_type(8))) short short8;
typedef __attribute__((ext_vector_type(4))) float float4v;

// ---------- one-pass CSR build, XCD-bucketed (R0-exact: best measured 77us) ----------
// block b: dst bucket (b&7), edge segment (b>>3). Each bucket's blocks write a
// contiguous 2.4 MB csr region -> scatter lines assemble in one XCD's L2.
// Structural limit: 1.6M device-scope atomicAdd-with-return ~ 20 G/s service
// rate (R2 nt-loads: 80us, R3 wg-scope+tickets: 110us — both worse).
__global__ __launch_bounds__(256) void k_count_fill_b(const int* __restrict__ ei,
        int* __restrict__ cnt, int* __restrict__ csr48) {
    int bucket = blockIdx.x & 7;
    int seg = blockIdx.x >> 3;
    int lo = bucket * NODES_PER_BUCKET, hi = lo + NODES_PER_BUCKET;
    int q1 = min((seg + 1) * QPS, QUADS);
    for (int q = seg * QPS + threadIdx.x; q < q1; q += 256) {
        int e0 = q * 4;
        int4 s = *(const int4*)(ei + e0);
        int4 d = *(const int4*)(ei + NE + e0);
        int r;
        if (d.x >= lo && d.x < hi) { r = atomicAdd(&cnt[d.x], 1); if (r < SLOTS) csr48[d.x * SLOTS + r] = s.x; }
        if (d.y >= lo && d.y < hi) { r = atomicAdd(&cnt[d.y], 1); if (r < SLOTS) csr48[d.y * SLOTS + r] = s.y; }
        if (d.z >= lo && d.z < hi) { r = atomicAdd(&cnt[d.z], 1); if (r < SLOTS) csr48[d.z * SLOTS + r] = s.z; }
        if (d.w >= lo && d.w < hi) { r = atomicAdd(&cnt[d.w], 1); if (r < SLOTS) csr48[d.w * SLOTS + r] = s.w; }
    }
}

// ---------------- prescale: xs = bf16(dinv[i]*x[i]); also emits dinv from cnt ----------------
__global__ __launch_bounds__(256) void k_prescale(const float* __restrict__ x,
        const int* __restrict__ cnt, float* __restrict__ dinv, unsigned short* __restrict__ xs) {
    int i = blockIdx.x * 256 + threadIdx.x;   // NN*32 threads, 4 feats each
    if (i >= NN * 32) return;
    int node = i >> 5, c = (i & 31) << 2;
    float d = rsqrtf((float)(cnt[node] + 1));  // +1 = self loop
    if ((i & 31) == 0) dinv[node] = d;
    float4 v = *(const float4*)(x + (size_t)node * 128 + c);
    uint2 st;
    st.x = ((unsigned int)f2bf(d * v.y) << 16) | f2bf(d * v.x);
    st.y = ((unsigned int)f2bf(d * v.w) << 16) | f2bf(d * v.z);
    *(uint2*)(xs + (size_t)node * 128 + c) = st;
}

// ---------------- merged weight transpose + downcast ----------------
__global__ void k_wt(const float* __restrict__ W1, const float* __restrict__ Wmu,
                     const float* __restrict__ Wls,
                     unsigned short* __restrict__ W1t, unsigned short* __restrict__ W2t) {
    int idx = blockIdx.x * 256 + threadIdx.x;   // 32768
    if (idx < 16384) {
        int n = idx >> 7, k = idx & 127;
        W1t[n * 128 + k] = f2bf(W1[k * 128 + n]);          // W1 [128][128]
    } else {
        int j = idx - 16384;
        int n = j >> 7, k = j & 127;                       // Wmu/Wls [128][64]
        float v = (n < 64) ? Wmu[k * 64 + n] : Wls[k * 64 + (n - 64)];
        W2t[n * 128 + k] = f2bf(v);
    }
}

// ---------------- gather core: quarter-wave per edge slot, 16B loads (R0-exact) ----------------
// lane = q*16 + l16; quarter q takes edge slots {q, q+4, ...}; lane covers 8 feats.
__device__ __forceinline__ void gather_core(
    const unsigned short* __restrict__ tab,
    const int* __restrict__ csr, int base, int deg,
    int q, int l16, float* a) {
    int t = q;
    while (t + 4 < deg) {   // 2 edges per quarter in flight (8/wave)
        int s0 = csr[base + t];
        int s1 = csr[base + t + 4];
        uint4 r0 = *(const uint4*)(tab + (size_t)s0 * 128 + l16 * 8);
        uint4 r1 = *(const uint4*)(tab + (size_t)s1 * 128 + l16 * 8);
        a[0] += bf2f(r0.x & 0xffffu) + bf2f(r1.x & 0xffffu);
        a[1] += bf2f(r0.x >> 16)     + bf2f(r1.x >> 16);
        a[2] += bf2f(r0.y & 0xffffu) + bf2f(r1.y & 0xffffu);
        a[3] += bf2f(r0.y >> 16)     + bf2f(r1.y >> 16);
        a[4] += bf2f(r0.z & 0xffffu) + bf2f(r1.z & 0xffffu);
        a[5] += bf2f(r0.z >> 16)     + bf2f(r1.z >> 16);
        a[6] += bf2f(r0.w & 0xffffu) + bf2f(r1.w & 0xffffu);
        a[7] += bf2f(r0.w >> 16)     + bf2f(r1.w >> 16);
        t += 8;
    }
    while (t < deg) {
        int s = csr[base + t];
        uint4 r = *(const uint4*)(tab + (size_t)s * 128 + l16 * 8);
        a[0] += bf2f(r.x & 0xffffu); a[1] += bf2f(r.x >> 16);
        a[2] += bf2f(r.y & 0xffffu); a[3] += bf2f(r.y >> 16);
        a[4] += bf2f(r.z & 0xffffu); a[5] += bf2f(r.z >> 16);
        a[6] += bf2f(r.w & 0xffffu); a[7] += bf2f(r.w >> 16);
        t += 4;
    }
}

// Gather one node's aggregated+scaled row straight into the LDS A-tile.
// Produces bf16 values bit-identical to the unfused gatherA global path.
__device__ __forceinline__ void gather_node_to_lds(
    const unsigned short* __restrict__ tab, const int* __restrict__ cnt,
    const int* __restrict__ csr48, const float* __restrict__ dinv,
    unsigned short* __restrict__ As, int row, int node,
    int q, int l16) {
    float a[8] = {0.f, 0.f, 0.f, 0.f, 0.f, 0.f, 0.f, 0.f};
    bool ok = node < NN;
    if (ok) {
        if (q == 0) {  // self term
            uint4 p = *(const uint4*)(tab + (size_t)node * 128 + l16 * 8);
            a[0] = bf2f(p.x & 0xffffu); a[1] = bf2f(p.x >> 16);
            a[2] = bf2f(p.y & 0xffffu); a[3] = bf2f(p.y >> 16);
            a[4] = bf2f(p.z & 0xffffu); a[5] = bf2f(p.z >> 16);
            a[6] = bf2f(p.w & 0xffffu); a[7] = bf2f(p.w >> 16);
        }
        int deg = __builtin_amdgcn_readfirstlane(cnt[node]);
        if (deg > SLOTS) deg = SLOTS;
        gather_core(tab, csr48, node * SLOTS, deg, q, l16, a);
#pragma unroll
        for (int j = 0; j < 8; ++j) {
            a[j] += __shfl_xor(a[j], 16);
            a[j] += __shfl_xor(a[j], 32);
        }
    }
    if (q == 0) {
        float di = ok ? dinv[node] : 0.f;
        uint4 st;
        st.x = ((unsigned int)f2bf(a[1] * di) << 16) | f2bf(a[0] * di);
        st.y = ((unsigned int)f2bf(a[3] * di) << 16) | f2bf(a[2] * di);
        st.z = ((unsigned int)f2bf(a[5] * di) << 16) | f2bf(a[4] * di);
        st.w = ((unsigned int)f2bf(a[7] * di) << 16) | f2bf(a[6] * di);
        *(uint4*)(As + row * 136 + l16 * 8) = st;   // byte off = row*272 + l16*16, 16B-aligned
    }
}

// ---------------- fused gather1 + GEMM1: hs = bf16(dinv * ((A~ xs) @ W1 + b1)) ----------------
// Block owns 64 nodes; each wave gathers 16 of them directly into the LDS
// A-tile (saves the y1 global write + re-read, 51.2 MB), then the MFMA body.
__global__ __launch_bounds__(256) void k_fuse1(
    const unsigned short* __restrict__ tab,  // xs [NN][128] bf16
    const int* __restrict__ cnt, const int* __restrict__ csr48,
    const float* __restrict__ dinv,
    const unsigned short* __restrict__ Bt,   // W1t [128][128] bf16 (n-major, k-contig)
    const float* __restrict__ bias,          // b1 [128]
    unsigned short* __restrict__ yout) {     // hs [NN][128] bf16 (layer-2 table)
    __shared__ __align__(16) unsigned short As[64 * 136];
    int tid = threadIdx.x;
    int lane = tid & 63, wave = tid >> 6;
    int q = lane >> 4, l16 = lane & 15;
    int r0 = blockIdx.x * 64;
#pragma unroll 1
    for (int rr = 0; rr < 16; ++rr) {
        int row = wave * 16 + rr;
        gather_node_to_lds(tab, cnt, csr48, dinv, As, row, r0 + row, q, l16);
    }
    __syncthreads();
    int quad = lane >> 4;
    int c0 = wave * 16 + l16;
    int c1 = 64 + c0;
    float4v acc[4][2];
#pragma unroll
    for (int rt = 0; rt < 4; ++rt) {
        float4v z = {0.f, 0.f, 0.f, 0.f};
        acc[rt][0] = z; acc[rt][1] = z;
    }
#pragma unroll
    for (int ks = 0; ks < 4; ++ks) {
        short8 b0 = *(const short8*)(Bt + (size_t)c0 * 128 + ks * 32 + quad * 8);
        short8 b1 = *(const short8*)(Bt + (size_t)c1 * 128 + ks * 32 + quad * 8);
        short8 af[4];
#pragma unroll
        for (int rt = 0; rt < 4; ++rt)
            af[rt] = *(const short8*)(As + (rt * 16 + l16) * 136 + ks * 32 + quad * 8);
#pragma unroll
        for (int rt = 0; rt < 4; ++rt) {
            acc[rt][0] = __builtin_amdgcn_mfma_f32_16x16x32_bf16(af[rt], b0, acc[rt][0], 0, 0, 0);
            acc[rt][1] = __builtin_amdgcn_mfma_f32_16x16x32_bf16(af[rt], b1, acc[rt][1], 0, 0, 0);
        }
    }
    float bc0 = bias[c0], bc1 = bias[c1];
#pragma unroll
    for (int rt = 0; rt < 4; ++rt)
#pragma unroll
        for (int reg = 0; reg < 4; ++reg) {
            int gr = r0 + rt * 16 + quad * 4 + reg;
            if (gr < NN) {
                float dg = dinv[gr];
                yout[(size_t)gr * 128 + c0] = f2bf(dg * (acc[rt][0][reg] + bc0));
                yout[(size_t)gr * 128 + c1] = f2bf(dg * (acc[rt][1][reg] + bc1));
            }
        }
}

// ------- fused gather2 + GEMM2 + epilogue: out = mu + init*exp(ls), [mu|ls] = (A~ hs) @ W2t -------
__global__ __launch_bounds__(256) void k_fuse2(
    const unsigned short* __restrict__ tab,  // hs [NN][128] bf16
    const int* __restrict__ cnt, const int* __restrict__ csr48,
    const float* __restrict__ dinv,
    const unsigned short* __restrict__ Bt,   // W2t [128][128] bf16
    const float* __restrict__ bmu,
    const float* __restrict__ bls,
    const float* __restrict__ init,
    float* __restrict__ outp) {
    __shared__ __align__(16) unsigned short As[64 * 136];
    int tid = threadIdx.x;
    int lane = tid & 63, wave = tid >> 6;
    int q = lane >> 4, l16 = lane & 15;
    int r0 = blockIdx.x * 64;
#pragma unroll 1
    for (int rr = 0; rr < 16; ++rr) {
        int row = wave * 16 + rr;
        gather_node_to_lds(tab, cnt, csr48, dinv, As, row, r0 + row, q, l16);
    }
    __syncthreads();
    int quad = lane >> 4;
    int cm = wave * 16 + l16;        // mu col (0..63)
    int cl = 64 + cm;                // matching ls col
    float4v acc[4][2];
#pragma unroll
    for (int rt = 0; rt < 4; ++rt) {
        float4v z = {0.f, 0.f, 0.f, 0.f};
        acc[rt][0] = z; acc[rt][1] = z;
    }
#pragma unroll
    for (int ks = 0; ks < 4; ++ks) {
        short8 b0 = *(const short8*)(Bt + (size_t)cm * 128 + ks * 32 + quad * 8);
        short8 b1 = *(const short8*)(Bt + (size_t)cl * 128 + ks * 32 + quad * 8);
        short8 af[4];
#pragma unroll
        for (int rt = 0; rt < 4; ++rt)
            af[rt] = *(const short8*)(As + (rt * 16 + l16) * 136 + ks * 32 + quad * 8);
#pragma unroll
        for (int rt = 0; rt < 4; ++rt) {
            acc[rt][0] = __builtin_amdgcn_mfma_f32_16x16x32_bf16(af[rt], b0, acc[rt][0], 0, 0, 0);
            acc[rt][1] = __builtin_amdgcn_mfma_f32_16x16x32_bf16(af[rt], b1, acc[rt][1], 0, 0, 0);
        }
    }
    float bc_mu = bmu[cm], bc_ls = bls[cm];
#pragma unroll
    for (int rt = 0; rt < 4; ++rt)
#pragma unroll
        for (int reg = 0; reg < 4; ++reg) {
            int gr = r0 + rt * 16 + quad * 4 + reg;
            if (gr < NN) {
                float mu = acc[rt][0][reg] + bc_mu;
                float ls = acc[rt][1][reg] + bc_ls;
                float idv = init[(size_t)gr * 64 + cm];
                outp[(size_t)gr * 64 + cm] = mu + idv * expf(ls);
            }
        }
}

extern "C" void kernel_launch(void* const* d_in, const int* in_sizes, int n_in,
                              void* d_out, int out_size, void* d_ws, size_t ws_size,
                              hipStream_t stream) {
    const float* x   = (const float*)d_in[0];  // [N,128] f32
    const int*   ei  = (const int*)d_in[1];    // [2,E] int32
    const float* ind = (const float*)d_in[2];  // [N,64] f32
    const float* W1  = (const float*)d_in[3];  // [128,128] f32
    const float* b1  = (const float*)d_in[4];  // [128] f32
    const float* Wmu = (const float*)d_in[5];  // [128,64] f32
    const float* bmu = (const float*)d_in[6];  // [64] f32
    const float* Wls = (const float*)d_in[7];  // [128,64] f32
    const float* bls = (const float*)d_in[8];  // [64] f32
    float* outp = (float*)d_out;               // [N,64] f32

    char* w = (char*)d_ws;
    auto carve = [&](size_t bytes) -> char* {
        char* p = w; w += (bytes + 255) & ~(size_t)255; return p;
    };
    int*   cnt  = (int*)carve((size_t)NN * 4);
    float* dinv = (float*)carve((size_t)NN * 4);
    unsigned short* W1t = (unsigned short*)carve(128 * 128 * 2);
    unsigned short* W2t = (unsigned short*)carve(128 * 128 * 2);
    unsigned short* xs  = (unsigned short*)carve((size_t)NN * 128 * 2);  // layer-1 table
    unsigned short* y   = (unsigned short*)carve((size_t)NN * 128 * 2);  // hs = layer-2 table
    int* csr = (int*)carve((size_t)NN * SLOTS * 4);
    // ~71.5 MB total — proven to fit

    hipMemsetAsync(cnt, 0, (size_t)NN * 4, stream);
    k_wt<<<128, 256, 0, stream>>>(W1, Wmu, Wls, W1t, W2t);
    k_count_fill_b<<<8 * SEGS, 256, 0, stream>>>(ei, cnt, csr);
    k_prescale<<<(NN * 32 + 255) / 256, 256, 0, stream>>>(x, cnt, dinv, xs);
    k_fuse1<<<(NN + 63) / 64, 256, 0, stream>>>(xs, cnt, csr, dinv, W1t, b1, y);
    k_fuse2<<<(NN + 63) / 64, 256, 0, stream>>>(y, cnt, csr, dinv, W2t, bmu, bls, ind, outp);
}

// Round 6
// 391.890 us; speedup vs baseline: 1.1812x; 1.1812x over previous
//
#include <hip/hip_runtime.h>
#include <math.h>

#define NN 100000
#define NE 1600000
#define SLOTS 48           // fixed csr stride; P(deg>=48) ~ 6e-11 per node
#define NODES_PER_BUCKET 12500   // 8 buckets x 12500 = NN
#define SEGS 256
#define QUADS (NE / 4)     // 400000
#define QPS ((QUADS + SEGS - 1) / SEGS)  // 1563

// bf16 <-> f32 helpers (bf16 stored as raw ushort; value<<16 == f32 bits)
__device__ __forceinline__ float bf2f(unsigned int u) {
    union { unsigned int u; float f; } c; c.u = u << 16; return c.f;
}
__device__ __forceinline__ unsigned short f2bf(float f) {
    union { float f; unsigned int u; } c; c.f = f;
    unsigned int x = c.u;
    return (unsigned short)((x + 0x7fffu + ((x >> 16) & 1u)) >> 16); // RNE
}

typedef __attribute__((ext_vector_type(4))) unsigned int uint4v;  // nt-store-compatible
typedef __attribute__((ext_vector_type(8))) short short8;
typedef __attribute__((ext_vector_type(4))) float float4v;

// ---------- one-pass CSR build, XCD-bucketed (R0-exact: best measured 77us) ----------
// Structural limit: 1.6M device-scope atomicAdd-with-return ~ 20 G/s service
// rate (R2 nt-loads: 80us, R3 wg-scope+tickets: 110us — both worse).
__global__ __launch_bounds__(256) void k_count_fill_b(const int* __restrict__ ei,
        int* __restrict__ cnt, int* __restrict__ csr48) {
    int bucket = blockIdx.x & 7;
    int seg = blockIdx.x >> 3;
    int lo = bucket * NODES_PER_BUCKET, hi = lo + NODES_PER_BUCKET;
    int q1 = min((seg + 1) * QPS, QUADS);
    for (int q = seg * QPS + threadIdx.x; q < q1; q += 256) {
        int e0 = q * 4;
        int4 s = *(const int4*)(ei + e0);
        int4 d = *(const int4*)(ei + NE + e0);
        int r;
        if (d.x >= lo && d.x < hi) { r = atomicAdd(&cnt[d.x], 1); if (r < SLOTS) csr48[d.x * SLOTS + r] = s.x; }
        if (d.y >= lo && d.y < hi) { r = atomicAdd(&cnt[d.y], 1); if (r < SLOTS) csr48[d.y * SLOTS + r] = s.y; }
        if (d.z >= lo && d.z < hi) { r = atomicAdd(&cnt[d.z], 1); if (r < SLOTS) csr48[d.z * SLOTS + r] = s.z; }
        if (d.w >= lo && d.w < hi) { r = atomicAdd(&cnt[d.w], 1); if (r < SLOTS) csr48[d.w * SLOTS + r] = s.w; }
    }
}

// ---------------- prescale: xs = bf16(dinv[i]*x[i]); also emits dinv from cnt ----------------
__global__ __launch_bounds__(256) void k_prescale(const float* __restrict__ x,
        const int* __restrict__ cnt, float* __restrict__ dinv, unsigned short* __restrict__ xs) {
    int i = blockIdx.x * 256 + threadIdx.x;   // NN*32 threads, 4 feats each
    if (i >= NN * 32) return;
    int node = i >> 5, c = (i & 31) << 2;
    float d = rsqrtf((float)(cnt[node] + 1));  // +1 = self loop
    if ((i & 31) == 0) dinv[node] = d;
    float4 v = *(const float4*)(x + (size_t)node * 128 + c);
    uint2 st;
    st.x = ((unsigned int)f2bf(d * v.y) << 16) | f2bf(d * v.x);
    st.y = ((unsigned int)f2bf(d * v.w) << 16) | f2bf(d * v.z);
    *(uint2*)(xs + (size_t)node * 128 + c) = st;
}

// ---------------- merged weight transpose + downcast ----------------
__global__ void k_wt(const float* __restrict__ W1, const float* __restrict__ Wmu,
                     const float* __restrict__ Wls,
                     unsigned short* __restrict__ W1t, unsigned short* __restrict__ W2t) {
    int idx = blockIdx.x * 256 + threadIdx.x;   // 32768
    if (idx < 16384) {
        int n = idx >> 7, k = idx & 127;
        W1t[n * 128 + k] = f2bf(W1[k * 128 + n]);          // W1 [128][128]
    } else {
        int j = idx - 16384;
        int n = j >> 7, k = j & 127;                       // Wmu/Wls [128][64]
        float v = (n < 64) ? Wmu[k * 64 + n] : Wls[k * 64 + (n - 64)];
        W2t[n * 128 + k] = f2bf(v);
    }
}

// ---------------- gather: quarter-wave per edge slot, 16B loads (R0-exact core) ----------------
// lane = q*16 + l16; quarter q takes edge slots {q, q+4, ...}; lane covers 8 feats.
__device__ __forceinline__ void gather_core(
    const unsigned short* __restrict__ tab,
    const int* __restrict__ csr, int base, int deg,
    int q, int l16, float* a) {
    int t = q;
    while (t + 4 < deg) {   // 2 edges per quarter in flight (8/wave)
        int s0 = csr[base + t];
        int s1 = csr[base + t + 4];
        uint4 r0 = *(const uint4*)(tab + (size_t)s0 * 128 + l16 * 8);
        uint4 r1 = *(const uint4*)(tab + (size_t)s1 * 128 + l16 * 8);
        a[0] += bf2f(r0.x & 0xffffu) + bf2f(r1.x & 0xffffu);
        a[1] += bf2f(r0.x >> 16)     + bf2f(r1.x >> 16);
        a[2] += bf2f(r0.y & 0xffffu) + bf2f(r1.y & 0xffffu);
        a[3] += bf2f(r0.y >> 16)     + bf2f(r1.y >> 16);
        a[4] += bf2f(r0.z & 0xffffu) + bf2f(r1.z & 0xffffu);
        a[5] += bf2f(r0.z >> 16)     + bf2f(r1.z >> 16);
        a[6] += bf2f(r0.w & 0xffffu) + bf2f(r1.w & 0xffffu);
        a[7] += bf2f(r0.w >> 16)     + bf2f(r1.w >> 16);
        t += 8;
    }
    while (t < deg) {
        int s = csr[base + t];
        uint4 r = *(const uint4*)(tab + (size_t)s * 128 + l16 * 8);
        a[0] += bf2f(r.x & 0xffffu); a[1] += bf2f(r.x >> 16);
        a[2] += bf2f(r.y & 0xffffu); a[3] += bf2f(r.y >> 16);
        a[4] += bf2f(r.z & 0xffffu); a[5] += bf2f(r.z >> 16);
        a[6] += bf2f(r.w & 0xffffu); a[7] += bf2f(r.w >> 16);
        t += 4;
    }
}

__global__ __launch_bounds__(256) void k_gatherA(
    const unsigned short* __restrict__ tab, const int* __restrict__ cnt,
    const int* __restrict__ csr48, const float* __restrict__ dinv,
    unsigned short* __restrict__ yout) {
    int node = blockIdx.x * 4 + (threadIdx.x >> 6);   // NN % 4 == 0
    int lane = threadIdx.x & 63;
    int q = lane >> 4, l16 = lane & 15;
    float a[8] = {0.f, 0.f, 0.f, 0.f, 0.f, 0.f, 0.f, 0.f};
    if (q == 0) {  // self term
        uint4 p = *(const uint4*)(tab + (size_t)node * 128 + l16 * 8);
        a[0] = bf2f(p.x & 0xffffu); a[1] = bf2f(p.x >> 16);
        a[2] = bf2f(p.y & 0xffffu); a[3] = bf2f(p.y >> 16);
        a[4] = bf2f(p.z & 0xffffu); a[5] = bf2f(p.z >> 16);
        a[6] = bf2f(p.w & 0xffffu); a[7] = bf2f(p.w >> 16);
    }
    int deg = __builtin_amdgcn_readfirstlane(cnt[node]);
    if (deg > SLOTS) deg = SLOTS;
    gather_core(tab, csr48, node * SLOTS, deg, q, l16, a);
#pragma unroll
    for (int j = 0; j < 8; ++j) {
        a[j] += __shfl_xor(a[j], 16);
        a[j] += __shfl_xor(a[j], 32);
    }
    if (q == 0) {
        float di = dinv[node];
        uint4v st;
        st.x = ((unsigned int)f2bf(a[1] * di) << 16) | f2bf(a[0] * di);
        st.y = ((unsigned int)f2bf(a[3] * di) << 16) | f2bf(a[2] * di);
        st.z = ((unsigned int)f2bf(a[5] * di) << 16) | f2bf(a[4] * di);
        st.w = ((unsigned int)f2bf(a[7] * di) << 16) | f2bf(a[6] * di);
        // NT store: output is single-use by the NEXT kernel; write-allocate here
        // evicts table lines from L2 during the latency-critical gather.
        __builtin_nontemporal_store(st, (uint4v*)(yout + (size_t)node * 128 + l16 * 8));
    }
}

// ---------------- GEMM1 (in-place layout): hs = bf16(dinv * (y @ W1 + b1)) ----------------
__global__ __launch_bounds__(256) void k_gemm1(
    unsigned short* __restrict__ yio,        // [NN][128] bf16 (y1 in, hs out)
    const unsigned short* __restrict__ Bt,   // [128][128] bf16 W1t (n-major, k-contig)
    const float* __restrict__ bias,          // [128] f32
    const float* __restrict__ dinv,
    int nrows) {
    __shared__ __align__(16) unsigned short As[64 * 136];
    int tid = threadIdx.x;
    int r0 = blockIdx.x * 64;
    for (int c = tid; c < 1024; c += 256) {
        int row = c >> 4, kc = (c & 15) << 3;
        int gr = r0 + row;
        short8 v = {0, 0, 0, 0, 0, 0, 0, 0};
        if (gr < nrows) v = *(const short8*)(yio + (size_t)gr * 128 + kc);
        *(short8*)(As + row * 136 + kc) = v;
    }
    __syncthreads();
    int lane = tid & 63, wave = tid >> 6;
    int quad = lane >> 4, l16 = lane & 15;
    int c0 = wave * 16 + l16;
    int c1 = 64 + c0;
    float4v acc[4][2];
#pragma unroll
    for (int rt = 0; rt < 4; ++rt) {
        float4v z = {0.f, 0.f, 0.f, 0.f};
        acc[rt][0] = z; acc[rt][1] = z;
    }
#pragma unroll
    for (int ks = 0; ks < 4; ++ks) {
        short8 b0 = *(const short8*)(Bt + (size_t)c0 * 128 + ks * 32 + quad * 8);
        short8 b1 = *(const short8*)(Bt + (size_t)c1 * 128 + ks * 32 + quad * 8);
        short8 af[4];
#pragma unroll
        for (int rt = 0; rt < 4; ++rt)
            af[rt] = *(const short8*)(As + (rt * 16 + l16) * 136 + ks * 32 + quad * 8);
#pragma unroll
        for (int rt = 0; rt < 4; ++rt) {
            acc[rt][0] = __builtin_amdgcn_mfma_f32_16x16x32_bf16(af[rt], b0, acc[rt][0], 0, 0, 0);
            acc[rt][1] = __builtin_amdgcn_mfma_f32_16x16x32_bf16(af[rt], b1, acc[rt][1], 0, 0, 0);
        }
    }
    float bc0 = bias[c0], bc1 = bias[c1];
#pragma unroll
    for (int rt = 0; rt < 4; ++rt)
#pragma unroll
        for (int reg = 0; reg < 4; ++reg) {
            int gr = r0 + rt * 16 + quad * 4 + reg;
            if (gr < nrows) {
                float dg = dinv[gr];
                unsigned short v0 = f2bf(dg * (acc[rt][0][reg] + bc0));
                unsigned short v1 = f2bf(dg * (acc[rt][1][reg] + bc1));
                __builtin_nontemporal_store(v0, yio + (size_t)gr * 128 + c0);
                __builtin_nontemporal_store(v1, yio + (size_t)gr * 128 + c1);
            }
        }
}

// ---------- GEMM2 + epilogue: [mu|ls] = y2 @ W2t + [bmu|bls]; out = mu + init*exp(ls) ----------
__global__ __launch_bounds__(256) void k_gemm2(
    const unsigned short* __restrict__ y2,
    const unsigned short* __restrict__ Bt,
    const float* __restrict__ bmu,
    const float* __restrict__ bls,
    const float* __restrict__ init,
    float* __restrict__ outp,
    int nrows) {
    __shared__ __align__(16) unsigned short As[64 * 136];
    int tid = threadIdx.x;
    int r0 = blockIdx.x * 64;
    for (int c = tid; c < 1024; c += 256) {
        int row = c >> 4, kc = (c & 15) << 3;
        int gr = r0 + row;
        short8 v = {0, 0, 0, 0, 0, 0, 0, 0};
        if (gr < nrows) v = *(const short8*)(y2 + (size_t)gr * 128 + kc);
        *(short8*)(As + row * 136 + kc) = v;
    }
    __syncthreads();
    int lane = tid & 63, wave = tid >> 6;
    int quad = lane >> 4, l16 = lane & 15;
    int cm = wave * 16 + l16;        // mu col (0..63)
    int cl = 64 + cm;                // matching ls col
    float4v acc[4][2];
#pragma unroll
    for (int rt = 0; rt < 4; ++rt) {
        float4v z = {0.f, 0.f, 0.f, 0.f};
        acc[rt][0] = z; acc[rt][1] = z;
    }
#pragma unroll
    for (int ks = 0; ks < 4; ++ks) {
        short8 b0 = *(const short8*)(Bt + (size_t)cm * 128 + ks * 32 + quad * 8);
        short8 b1 = *(const short8*)(Bt + (size_t)cl * 128 + ks * 32 + quad * 8);
        short8 af[4];
#pragma unroll
        for (int rt = 0; rt < 4; ++rt)
            af[rt] = *(const short8*)(As + (rt * 16 + l16) * 136 + ks * 32 + quad * 8);
#pragma unroll
        for (int rt = 0; rt < 4; ++rt) {
            acc[rt][0] = __builtin_amdgcn_mfma_f32_16x16x32_bf16(af[rt], b0, acc[rt][0], 0, 0, 0);
            acc[rt][1] = __builtin_amdgcn_mfma_f32_16x16x32_bf16(af[rt], b1, acc[rt][1], 0, 0, 0);
        }
    }
    float bc_mu = bmu[cm], bc_ls = bls[cm];
#pragma unroll
    for (int rt = 0; rt < 4; ++rt)
#pragma unroll
        for (int reg = 0; reg < 4; ++reg) {
            int gr = r0 + rt * 16 + quad * 4 + reg;
            if (gr < nrows) {
                float mu = acc[rt][0][reg] + bc_mu;
                float ls = acc[rt][1][reg] + bc_ls;
                float idv = __builtin_nontemporal_load(init + (size_t)gr * 64 + cm);
                float ov = mu + idv * expf(ls);
                __builtin_nontemporal_store(ov, outp + (size_t)gr * 64 + cm);
            }
        }
}

extern "C" void kernel_launch(void* const* d_in, const int* in_sizes, int n_in,
                              void* d_out, int out_size, void* d_ws, size_t ws_size,
                              hipStream_t stream) {
    const float* x   = (const float*)d_in[0];  // [N,128] f32
    const int*   ei  = (const int*)d_in[1];    // [2,E] int32
    const float* ind = (const float*)d_in[2];  // [N,64] f32
    const float* W1  = (const float*)d_in[3];  // [128,128] f32
    const float* b1  = (const float*)d_in[4];  // [128] f32
    const float* Wmu = (const float*)d_in[5];  // [128,64] f32
    const float* bmu = (const float*)d_in[6];  // [64] f32
    const float* Wls = (const float*)d_in[7];  // [128,64] f32
    const float* bls = (const float*)d_in[8];  // [64] f32
    float* outp = (float*)d_out;               // [N,64] f32

    char* w = (char*)d_ws;
    auto carve = [&](size_t bytes) -> char* {
        char* p = w; w += (bytes + 255) & ~(size_t)255; return p;
    };
    int*   cnt  = (int*)carve((size_t)NN * 4);
    float* dinv = (float*)carve((size_t)NN * 4);
    unsigned short* W1t = (unsigned short*)carve(128 * 128 * 2);
    unsigned short* W2t = (unsigned short*)carve(128 * 128 * 2);
    unsigned short* xs  = (unsigned short*)carve((size_t)NN * 128 * 2);  // xs -> y2
    unsigned short* y   = (unsigned short*)carve((size_t)NN * 128 * 2);  // y1 -> hs (in-place)
    int* csr = (int*)carve((size_t)NN * SLOTS * 4);
    // ~71.5 MB total — proven to fit

    hipMemsetAsync(cnt, 0, (size_t)NN * 4, stream);
    k_wt<<<128, 256, 0, stream>>>(W1, Wmu, Wls, W1t, W2t);
    k_count_fill_b<<<8 * SEGS, 256, 0, stream>>>(ei, cnt, csr);
    k_prescale<<<(NN * 32 + 255) / 256, 256, 0, stream>>>(x, cnt, dinv, xs);
    k_gatherA<<<NN / 4, 256, 0, stream>>>(xs, cnt, csr, dinv, y);           // y1
    k_gemm1<<<(NN + 63) / 64, 256, 0, stream>>>(y, W1t, b1, dinv, NN);      // y -> hs
    k_gatherA<<<NN / 4, 256, 0, stream>>>(y, cnt, csr, dinv, xs);           // y2
    k_gemm2<<<(NN + 63) / 64, 256, 0, stream>>>(xs, W2t, bmu, bls, ind, outp, NN);
}

// Round 7
// 376.193 us; speedup vs baseline: 1.2305x; 1.0417x over previous
//
#include <hip/hip_runtime.h>
#include <math.h>

#define NN 100000
#define NE 1600000
#define SLOTS 48           // fixed csr stride; P(deg>=48) ~ 6e-11 per node
#define NODES_PER_BUCKET 12500   // 8 buckets x 12500 = NN
#define SEGS 256
#define QUADS (NE / 4)     // 400000
#define QPS ((QUADS + SEGS - 1) / SEGS)  // 1563

// bf16 <-> f32 helpers (bf16 stored as raw ushort; value<<16 == f32 bits)
__device__ __forceinline__ float bf2f(unsigned int u) {
    union { unsigned int u; float f; } c; c.u = u << 16; return c.f;
}
__device__ __forceinline__ unsigned short f2bf(float f) {
    union { float f; unsigned int u; } c; c.f = f;
    unsigned int x = c.u;
    return (unsigned short)((x + 0x7fffu + ((x >> 16) & 1u)) >> 16); // RNE
}

typedef __attribute__((ext_vector_type(8))) short short8;
typedef __attribute__((ext_vector_type(4))) float float4v;

// ---------- one-pass CSR build, XCD-bucketed (R0-exact: best measured 77us) ----------
// Structural limit: 1.6M device-scope atomicAdd-with-return ~ 20 G/s service
// rate (R2 nt-loads: 80us, R3 wg-scope+tickets: 110us — both worse).
__global__ __launch_bounds__(256) void k_count_fill_b(const int* __restrict__ ei,
        int* __restrict__ cnt, int* __restrict__ csr48) {
    int bucket = blockIdx.x & 7;
    int seg = blockIdx.x >> 3;
    int lo = bucket * NODES_PER_BUCKET, hi = lo + NODES_PER_BUCKET;
    int q1 = min((seg + 1) * QPS, QUADS);
    for (int q = seg * QPS + threadIdx.x; q < q1; q += 256) {
        int e0 = q * 4;
        int4 s = *(const int4*)(ei + e0);
        int4 d = *(const int4*)(ei + NE + e0);
        int r;
        if (d.x >= lo && d.x < hi) { r = atomicAdd(&cnt[d.x], 1); if (r < SLOTS) csr48[d.x * SLOTS + r] = s.x; }
        if (d.y >= lo && d.y < hi) { r = atomicAdd(&cnt[d.y], 1); if (r < SLOTS) csr48[d.y * SLOTS + r] = s.y; }
        if (d.z >= lo && d.z < hi) { r = atomicAdd(&cnt[d.z], 1); if (r < SLOTS) csr48[d.z * SLOTS + r] = s.z; }
        if (d.w >= lo && d.w < hi) { r = atomicAdd(&cnt[d.w], 1); if (r < SLOTS) csr48[d.w * SLOTS + r] = s.w; }
    }
}

// ---------------- weight prep: W2c = bf16(W1 @ [Wmu|Wls]) (n-major,k-contig), ----------------
// bw = b1 @ [Wmu|Wls] (f32), and zero cnt (replaces k_wt + memset dispatches).
// Associativity: mu = G2(X)(W1 Wmu) + (G*1)(b1' Wmu) + bmu — gemm1 is eliminated.
__global__ __launch_bounds__(256) void k_wprep(const float* __restrict__ W1,
        const float* __restrict__ Wmu, const float* __restrict__ Wls,
        const float* __restrict__ b1,
        unsigned short* __restrict__ W2c, float* __restrict__ bw, int* __restrict__ cnt) {
    int idx = blockIdx.x * 256 + threadIdx.x;   // grid 96*256 = 24576
    if (idx < 16384) {
        int k = idx >> 7, n = idx & 127;        // k = input-feat (K dim), n = output col
        const float* Wx = (n < 64) ? (Wmu + n) : (Wls + (n - 64));  // column base, stride 64
        float s = 0.f;
#pragma unroll 8
        for (int m = 0; m < 128; ++m) s += W1[k * 128 + m] * Wx[(size_t)m * 64];
        W2c[n * 128 + k] = f2bf(s);
    } else if (idx < 16512) {
        int n = idx - 16384;
        const float* Wx = (n < 64) ? (Wmu + n) : (Wls + (n - 64));
        float s = 0.f;
        for (int m = 0; m < 128; ++m) s += b1[m] * Wx[(size_t)m * 64];
        bw[n] = s;
    } else {
        for (int i = idx - 16512; i < NN; i += 24576 - 16512) cnt[i] = 0;
    }
}

// ---------------- prescale: xs = bf16(dinv[i]*x[i]); also emits dinv from cnt ----------------
__global__ __launch_bounds__(256) void k_prescale(const float* __restrict__ x,
        const int* __restrict__ cnt, float* __restrict__ dinv, unsigned short* __restrict__ xs) {
    int i = blockIdx.x * 256 + threadIdx.x;   // NN*32 threads, 4 feats each
    if (i >= NN * 32) return;
    int node = i >> 5, c = (i & 31) << 2;
    float d = rsqrtf((float)(cnt[node] + 1));  // +1 = self loop
    if ((i & 31) == 0) dinv[node] = d;
    float4 v = *(const float4*)(x + (size_t)node * 128 + c);
    uint2 st;
    st.x = ((unsigned int)f2bf(d * v.y) << 16) | f2bf(d * v.x);
    st.y = ((unsigned int)f2bf(d * v.w) << 16) | f2bf(d * v.z);
    *(uint2*)(xs + (size_t)node * 128 + c) = st;
}

// ---------------- gather1: t1 = bf16(dinv^2 * sum xs[nbr]); avec = dinv*(dinv + sum dinv[nbr]) --
// R0-exact access pattern; adds the cheap dinv[src] accumulation (L2-hot broadcast).
__global__ __launch_bounds__(256) void k_gather1(
    const unsigned short* __restrict__ tab, const int* __restrict__ cnt,
    const int* __restrict__ csr48, const float* __restrict__ dinv,
    unsigned short* __restrict__ yout, float* __restrict__ avec) {
    int node = blockIdx.x * 4 + (threadIdx.x >> 6);   // NN % 4 == 0
    int lane = threadIdx.x & 63;
    int q = lane >> 4, l16 = lane & 15;
    float a[8] = {0.f, 0.f, 0.f, 0.f, 0.f, 0.f, 0.f, 0.f};
    float asum = 0.f;
    if (q == 0) {  // self term
        uint4 p = *(const uint4*)(tab + (size_t)node * 128 + l16 * 8);
        a[0] = bf2f(p.x & 0xffffu); a[1] = bf2f(p.x >> 16);
        a[2] = bf2f(p.y & 0xffffu); a[3] = bf2f(p.y >> 16);
        a[4] = bf2f(p.z & 0xffffu); a[5] = bf2f(p.z >> 16);
        a[6] = bf2f(p.w & 0xffffu); a[7] = bf2f(p.w >> 16);
    }
    int deg = __builtin_amdgcn_readfirstlane(cnt[node]);
    if (deg > SLOTS) deg = SLOTS;
    int base = node * SLOTS;
    int t = q;
    while (t + 4 < deg) {   // 2 edges per quarter in flight (8/wave)
        int s0 = csr48[base + t];
        int s1 = csr48[base + t + 4];
        uint4 r0 = *(const uint4*)(tab + (size_t)s0 * 128 + l16 * 8);
        uint4 r1 = *(const uint4*)(tab + (size_t)s1 * 128 + l16 * 8);
        asum += dinv[s0] + dinv[s1];
        a[0] += bf2f(r0.x & 0xffffu) + bf2f(r1.x & 0xffffu);
        a[1] += bf2f(r0.x >> 16)     + bf2f(r1.x >> 16);
        a[2] += bf2f(r0.y & 0xffffu) + bf2f(r1.y & 0xffffu);
        a[3] += bf2f(r0.y >> 16)     + bf2f(r1.y >> 16);
        a[4] += bf2f(r0.z & 0xffffu) + bf2f(r1.z & 0xffffu);
        a[5] += bf2f(r0.z >> 16)     + bf2f(r1.z >> 16);
        a[6] += bf2f(r0.w & 0xffffu) + bf2f(r1.w & 0xffffu);
        a[7] += bf2f(r0.w >> 16)     + bf2f(r1.w >> 16);
        t += 8;
    }
    while (t < deg) {
        int s = csr48[base + t];
        uint4 r = *(const uint4*)(tab + (size_t)s * 128 + l16 * 8);
        asum += dinv[s];
        a[0] += bf2f(r.x & 0xffffu); a[1] += bf2f(r.x >> 16);
        a[2] += bf2f(r.y & 0xffffu); a[3] += bf2f(r.y >> 16);
        a[4] += bf2f(r.z & 0xffffu); a[5] += bf2f(r.z >> 16);
        a[6] += bf2f(r.w & 0xffffu); a[7] += bf2f(r.w >> 16);
        t += 4;
    }
#pragma unroll
    for (int j = 0; j < 8; ++j) {
        a[j] += __shfl_xor(a[j], 16);
        a[j] += __shfl_xor(a[j], 32);
    }
    asum += __shfl_xor(asum, 16);
    asum += __shfl_xor(asum, 32);
    if (q == 0) {
        float di = dinv[node];
        float d2 = di * di;      // t1 = dinv * g1 = dinv^2 * sum(xs)
        uint4 st;
        st.x = ((unsigned int)f2bf(a[1] * d2) << 16) | f2bf(a[0] * d2);
        st.y = ((unsigned int)f2bf(a[3] * d2) << 16) | f2bf(a[2] * d2);
        st.z = ((unsigned int)f2bf(a[5] * d2) << 16) | f2bf(a[4] * d2);
        st.w = ((unsigned int)f2bf(a[7] * d2) << 16) | f2bf(a[6] * d2);
        *(uint4*)(yout + (size_t)node * 128 + l16 * 8) = st;
        if (l16 == 0) avec[node] = di * (asum + di);   // a = G*1
    }
}

// ---------------- gather2: g2 = bf16(dinv * sum t1[nbr])  (R0-exact gatherA) ----------------
__global__ __launch_bounds__(256) void k_gather2(
    const unsigned short* __restrict__ tab, const int* __restrict__ cnt,
    const int* __restrict__ csr48, const float* __restrict__ dinv,
    unsigned short* __restrict__ yout) {
    int node = blockIdx.x * 4 + (threadIdx.x >> 6);
    int lane = threadIdx.x & 63;
    int q = lane >> 4, l16 = lane & 15;
    float a[8] = {0.f, 0.f, 0.f, 0.f, 0.f, 0.f, 0.f, 0.f};
    if (q == 0) {  // self term
        uint4 p = *(const uint4*)(tab + (size_t)node * 128 + l16 * 8);
        a[0] = bf2f(p.x & 0xffffu); a[1] = bf2f(p.x >> 16);
        a[2] = bf2f(p.y & 0xffffu); a[3] = bf2f(p.y >> 16);
        a[4] = bf2f(p.z & 0xffffu); a[5] = bf2f(p.z >> 16);
        a[6] = bf2f(p.w & 0xffffu); a[7] = bf2f(p.w >> 16);
    }
    int deg = __builtin_amdgcn_readfirstlane(cnt[node]);
    if (deg > SLOTS) deg = SLOTS;
    int base = node * SLOTS;
    int t = q;
    while (t + 4 < deg) {
        int s0 = csr48[base + t];
        int s1 = csr48[base + t + 4];
        uint4 r0 = *(const uint4*)(tab + (size_t)s0 * 128 + l16 * 8);
        uint4 r1 = *(const uint4*)(tab + (size_t)s1 * 128 + l16 * 8);
        a[0] += bf2f(r0.x & 0xffffu) + bf2f(r1.x & 0xffffu);
        a[1] += bf2f(r0.x >> 16)     + bf2f(r1.x >> 16);
        a[2] += bf2f(r0.y & 0xffffu) + bf2f(r1.y & 0xffffu);
        a[3] += bf2f(r0.y >> 16)     + bf2f(r1.y >> 16);
        a[4] += bf2f(r0.z & 0xffffu) + bf2f(r1.z & 0xffffu);
        a[5] += bf2f(r0.z >> 16)     + bf2f(r1.z >> 16);
        a[6] += bf2f(r0.w & 0xffffu) + bf2f(r1.w & 0xffffu);
        a[7] += bf2f(r0.w >> 16)     + bf2f(r1.w >> 16);
        t += 8;
    }
    while (t < deg) {
        int s = csr48[base + t];
        uint4 r = *(const uint4*)(tab + (size_t)s * 128 + l16 * 8);
        a[0] += bf2f(r.x & 0xffffu); a[1] += bf2f(r.x >> 16);
        a[2] += bf2f(r.y & 0xffffu); a[3] += bf2f(r.y >> 16);
        a[4] += bf2f(r.z & 0xffffu); a[5] += bf2f(r.z >> 16);
        a[6] += bf2f(r.w & 0xffffu); a[7] += bf2f(r.w >> 16);
        t += 4;
    }
#pragma unroll
    for (int j = 0; j < 8; ++j) {
        a[j] += __shfl_xor(a[j], 16);
        a[j] += __shfl_xor(a[j], 32);
    }
    if (q == 0) {
        float di = dinv[node];
        uint4 st;
        st.x = ((unsigned int)f2bf(a[1] * di) << 16) | f2bf(a[0] * di);
        st.y = ((unsigned int)f2bf(a[3] * di) << 16) | f2bf(a[2] * di);
        st.z = ((unsigned int)f2bf(a[5] * di) << 16) | f2bf(a[4] * di);
        st.w = ((unsigned int)f2bf(a[7] * di) << 16) | f2bf(a[6] * di);
        *(uint4*)(yout + (size_t)node * 128 + l16 * 8) = st;
    }
}

// ---- gemmC + epilogue: [mu|ls] = g2 @ W2c + a (x) bw + [bmu|bls]; out = mu + init*exp(ls) ----
__global__ __launch_bounds__(256) void k_gemmC(
    const unsigned short* __restrict__ g2,   // [NN][128] bf16
    const unsigned short* __restrict__ Bt,   // W2c [128][128] bf16 (n-major, k-contig)
    const float* __restrict__ bw,            // [128] f32 (b1 @ [Wmu|Wls])
    const float* __restrict__ avec,          // [NN] f32
    const float* __restrict__ bmu,
    const float* __restrict__ bls,
    const float* __restrict__ init,
    float* __restrict__ outp,
    int nrows) {
    __shared__ __align__(16) unsigned short As[64 * 136];
    int tid = threadIdx.x;
    int r0 = blockIdx.x * 64;
    for (int c = tid; c < 1024; c += 256) {
        int row = c >> 4, kc = (c & 15) << 3;
        int gr = r0 + row;
        short8 v = {0, 0, 0, 0, 0, 0, 0, 0};
        if (gr < nrows) v = *(const short8*)(g2 + (size_t)gr * 128 + kc);
        *(short8*)(As + row * 136 + kc) = v;
    }
    __syncthreads();
    int lane = tid & 63, wave = tid >> 6;
    int quad = lane >> 4, l16 = lane & 15;
    int cm = wave * 16 + l16;        // mu col (0..63)
    int cl = 64 + cm;                // matching ls col
    float4v acc[4][2];
#pragma unroll
    for (int rt = 0; rt < 4; ++rt) {
        float4v z = {0.f, 0.f, 0.f, 0.f};
        acc[rt][0] = z; acc[rt][1] = z;
    }
#pragma unroll
    for (int ks = 0; ks < 4; ++ks) {
        short8 b0 = *(const short8*)(Bt + (size_t)cm * 128 + ks * 32 + quad * 8);
        short8 b1 = *(const short8*)(Bt + (size_t)cl * 128 + ks * 32 + quad * 8);
        short8 af[4];
#pragma unroll
        for (int rt = 0; rt < 4; ++rt)
            af[rt] = *(const short8*)(As + (rt * 16 + l16) * 136 + ks * 32 + quad * 8);
#pragma unroll
        for (int rt = 0; rt < 4; ++rt) {
            acc[rt][0] = __builtin_amdgcn_mfma_f32_16x16x32_bf16(af[rt], b0, acc[rt][0], 0, 0, 0);
            acc[rt][1] = __builtin_amdgcn_mfma_f32_16x16x32_bf16(af[rt], b1, acc[rt][1], 0, 0, 0);
        }
    }
    float bc_mu = bmu[cm], bc_ls = bls[cm];
    float bwm = bw[cm], bwl = bw[cl];
#pragma unroll
    for (int rt = 0; rt < 4; ++rt)
#pragma unroll
        for (int reg = 0; reg < 4; ++reg) {
            int gr = r0 + rt * 16 + quad * 4 + reg;
            if (gr < nrows) {
                float av = avec[gr];
                float mu = acc[rt][0][reg] + av * bwm + bc_mu;
                float ls = acc[rt][1][reg] + av * bwl + bc_ls;
                float idv = init[(size_t)gr * 64 + cm];
                outp[(size_t)gr * 64 + cm] = mu + idv * expf(ls);
            }
        }
}

extern "C" void kernel_launch(void* const* d_in, const int* in_sizes, int n_in,
                              void* d_out, int out_size, void* d_ws, size_t ws_size,
                              hipStream_t stream) {
    const float* x   = (const float*)d_in[0];  // [N,128] f32
    const int*   ei  = (const int*)d_in[1];    // [2,E] int32
    const float* ind = (const float*)d_in[2];  // [N,64] f32
    const float* W1  = (const float*)d_in[3];  // [128,128] f32
    const float* b1  = (const float*)d_in[4];  // [128] f32
    const float* Wmu = (const float*)d_in[5];  // [128,64] f32
    const float* bmu = (const float*)d_in[6];  // [64] f32
    const float* Wls = (const float*)d_in[7];  // [128,64] f32
    const float* bls = (const float*)d_in[8];  // [64] f32
    float* outp = (float*)d_out;               // [N,64] f32

    char* w = (char*)d_ws;
    auto carve = [&](size_t bytes) -> char* {
        char* p = w; w += (bytes + 255) & ~(size_t)255; return p;
    };
    int*   cnt  = (int*)carve((size_t)NN * 4);
    float* dinv = (float*)carve((size_t)NN * 4);
    float* avec = (float*)carve((size_t)NN * 4);
    float* bw   = (float*)carve(128 * 4);
    unsigned short* W2c = (unsigned short*)carve(128 * 128 * 2);
    unsigned short* xs  = (unsigned short*)carve((size_t)NN * 128 * 2);  // xs, then g2 (aliased)
    unsigned short* t1  = (unsigned short*)carve((size_t)NN * 128 * 2);  // gather1 output
    int* csr = (int*)carve((size_t)NN * SLOTS * 4);
    // ~71.5 MB total — same as proven-fit layout (g2 aliases xs)

    k_wprep<<<96, 256, 0, stream>>>(W1, Wmu, Wls, b1, W2c, bw, cnt);   // also zeroes cnt
    k_count_fill_b<<<8 * SEGS, 256, 0, stream>>>(ei, cnt, csr);
    k_prescale<<<(NN * 32 + 255) / 256, 256, 0, stream>>>(x, cnt, dinv, xs);
    k_gather1<<<NN / 4, 256, 0, stream>>>(xs, cnt, csr, dinv, t1, avec);
    k_gather2<<<NN / 4, 256, 0, stream>>>(t1, cnt, csr, dinv, xs);      // g2 -> xs buffer
    k_gemmC<<<(NN + 63) / 64, 256, 0, stream>>>(xs, W2c, bw, avec, bmu, bls, ind, outp, NN);
}

// Round 8
// 355.979 us; speedup vs baseline: 1.3004x; 1.0568x over previous
//
#include <hip/hip_runtime.h>
#include <math.h>

#define NN 100000
#define NE 1600000
#define SLOTS 48           // fixed csr stride; P(deg>=48) ~ 6e-11 per node
#define NODES_PER_BUCKET 12500   // 8 buckets x 12500 = NN
#define QUADS (NE / 4)     // 400000
#define CSEG 128           // count-fill segments per bucket (1024 blocks total)
#define QPS2 ((QUADS + CSEG - 1) / CSEG)  // 3125
#define XCAST_T (NN * 32)            // 3,200,000 xcast threads
#define PREP_T (XCAST_T + 16384 + 128)
#define PREP_B ((PREP_T + 255) / 256)    // 12565
#define FRONT_B (1024 + PREP_B)

// bf16 <-> f32 helpers (bf16 stored as raw ushort; value<<16 == f32 bits)
__device__ __forceinline__ float bf2f(unsigned int u) {
    union { unsigned int u; float f; } c; c.u = u << 16; return c.f;
}
__device__ __forceinline__ unsigned short f2bf(float f) {
    union { float f; unsigned int u; } c; c.f = f;
    unsigned int x = c.u;
    return (unsigned short)((x + 0x7fffu + ((x >> 16) & 1u)) >> 16); // RNE
}

typedef __attribute__((ext_vector_type(8))) short short8;
typedef __attribute__((ext_vector_type(4))) float float4v;

// ---------- k_front: CSR build (1024 blocks, dispatched first) + indep prep ----------
// count_fill is atomic-service-rate bound (VALUBusy 3.8%, HBM 21% at 2048 blocks),
// so 1024 blocks should sustain the same rate while the prep blocks (xcast of x to
// bf16, W2c = W1@[Wmu|Wls], bw = b1@[Wmu|Wls]) fill the freed capacity concurrently.
// Associativity (R7): mu = G2(X)(W1 Wmu) + (G*1)(b1' Wmu) + bmu — no hidden-layer GEMM.
__global__ __launch_bounds__(256) void k_front(const int* __restrict__ ei,
        int* __restrict__ cnt, int* __restrict__ csr48,
        const float* __restrict__ x, unsigned short* __restrict__ xq,
        const float* __restrict__ W1, const float* __restrict__ Wmu,
        const float* __restrict__ Wls, const float* __restrict__ b1,
        unsigned short* __restrict__ W2c, float* __restrict__ bw) {
    int b = blockIdx.x;
    if (b < 1024) {
        int bucket = b & 7;
        int seg = b >> 3;                // 0..127
        int lo = bucket * NODES_PER_BUCKET, hi = lo + NODES_PER_BUCKET;
        int q1 = min((seg + 1) * QPS2, QUADS);
        for (int q = seg * QPS2 + (int)threadIdx.x; q < q1; q += 256) {
            int e0 = q * 4;
            int4 s = *(const int4*)(ei + e0);
            int4 d = *(const int4*)(ei + NE + e0);
            int r;
            if (d.x >= lo && d.x < hi) { r = atomicAdd(&cnt[d.x], 1); if (r < SLOTS) csr48[d.x * SLOTS + r] = s.x; }
            if (d.y >= lo && d.y < hi) { r = atomicAdd(&cnt[d.y], 1); if (r < SLOTS) csr48[d.y * SLOTS + r] = s.y; }
            if (d.z >= lo && d.z < hi) { r = atomicAdd(&cnt[d.z], 1); if (r < SLOTS) csr48[d.z * SLOTS + r] = s.z; }
            if (d.w >= lo && d.w < hi) { r = atomicAdd(&cnt[d.w], 1); if (r < SLOTS) csr48[d.w * SLOTS + r] = s.w; }
        }
    } else {
        int idx = (b - 1024) * 256 + (int)threadIdx.x;
        if (idx < XCAST_T) {
            // xcast: xq = bf16(x), NO dinv scaling (moved into gather1 on-the-fly)
            int node = idx >> 5, c = (idx & 31) << 2;
            float4 v = *(const float4*)(x + (size_t)node * 128 + c);
            uint2 st;
            st.x = ((unsigned int)f2bf(v.y) << 16) | f2bf(v.x);
            st.y = ((unsigned int)f2bf(v.w) << 16) | f2bf(v.z);
            *(uint2*)(xq + (size_t)node * 128 + c) = st;
        } else if (idx < XCAST_T + 16384) {
            int j = idx - XCAST_T;
            int k = j >> 7, n = j & 127;        // k = input feat (K dim), n = out col
            const float* Wx = (n < 64) ? (Wmu + n) : (Wls + (n - 64));  // col base, stride 64
            float s = 0.f;
#pragma unroll 8
            for (int m = 0; m < 128; ++m) s += W1[k * 128 + m] * Wx[(size_t)m * 64];
            W2c[n * 128 + k] = f2bf(s);
        } else if (idx < PREP_T) {
            int n = idx - XCAST_T - 16384;
            const float* Wx = (n < 64) ? (Wmu + n) : (Wls + (n - 64));
            float s = 0.f;
            for (int m = 0; m < 128; ++m) s += b1[m] * Wx[(size_t)m * 64];
            bw[n] = s;
        }
    }
}

// -------- gather1: t1 = bf16(dn^2 * (dn*x_n + sum_s d_s*xq_s)); avec = dn*(dn+sum d_s) --------
// R0-exact access pattern; per-source dinv computed on the fly from cnt (same
// memory traffic as the old dinv[] load, add->fma swap is VALU-neutral).
__global__ __launch_bounds__(256) void k_gather1(
    const unsigned short* __restrict__ tab, const int* __restrict__ cnt,
    const int* __restrict__ csr48,
    unsigned short* __restrict__ yout, float* __restrict__ avec) {
    int node = blockIdx.x * 4 + (threadIdx.x >> 6);   // NN % 4 == 0
    int lane = threadIdx.x & 63;
    int q = lane >> 4, l16 = lane & 15;
    int deg = __builtin_amdgcn_readfirstlane(cnt[node]);
    float dn = rsqrtf((float)(deg + 1));              // raw degree (+self)
    if (deg > SLOTS) deg = SLOTS;
    float a[8] = {0.f, 0.f, 0.f, 0.f, 0.f, 0.f, 0.f, 0.f};
    float asum = 0.f;
    if (q == 0) {  // self term, scaled by dn
        uint4 p = *(const uint4*)(tab + (size_t)node * 128 + l16 * 8);
        a[0] = dn * bf2f(p.x & 0xffffu); a[1] = dn * bf2f(p.x >> 16);
        a[2] = dn * bf2f(p.y & 0xffffu); a[3] = dn * bf2f(p.y >> 16);
        a[4] = dn * bf2f(p.z & 0xffffu); a[5] = dn * bf2f(p.z >> 16);
        a[6] = dn * bf2f(p.w & 0xffffu); a[7] = dn * bf2f(p.w >> 16);
    }
    int base = node * SLOTS;
    int t = q;
    while (t + 4 < deg) {   // 2 edges per quarter in flight (8/wave)
        int s0 = csr48[base + t];
        int s1 = csr48[base + t + 4];
        float d0 = rsqrtf((float)(cnt[s0] + 1));
        float d1 = rsqrtf((float)(cnt[s1] + 1));
        uint4 r0 = *(const uint4*)(tab + (size_t)s0 * 128 + l16 * 8);
        uint4 r1 = *(const uint4*)(tab + (size_t)s1 * 128 + l16 * 8);
        asum += d0 + d1;
        a[0] += d0 * bf2f(r0.x & 0xffffu) + d1 * bf2f(r1.x & 0xffffu);
        a[1] += d0 * bf2f(r0.x >> 16)     + d1 * bf2f(r1.x >> 16);
        a[2] += d0 * bf2f(r0.y & 0xffffu) + d1 * bf2f(r1.y & 0xffffu);
        a[3] += d0 * bf2f(r0.y >> 16)     + d1 * bf2f(r1.y >> 16);
        a[4] += d0 * bf2f(r0.z & 0xffffu) + d1 * bf2f(r1.z & 0xffffu);
        a[5] += d0 * bf2f(r0.z >> 16)     + d1 * bf2f(r1.z >> 16);
        a[6] += d0 * bf2f(r0.w & 0xffffu) + d1 * bf2f(r1.w & 0xffffu);
        a[7] += d0 * bf2f(r0.w >> 16)     + d1 * bf2f(r1.w >> 16);
        t += 8;
    }
    while (t < deg) {
        int s = csr48[base + t];
        float ds = rsqrtf((float)(cnt[s] + 1));
        uint4 r = *(const uint4*)(tab + (size_t)s * 128 + l16 * 8);
        asum += ds;
        a[0] += ds * bf2f(r.x & 0xffffu); a[1] += ds * bf2f(r.x >> 16);
        a[2] += ds * bf2f(r.y & 0xffffu); a[3] += ds * bf2f(r.y >> 16);
        a[4] += ds * bf2f(r.z & 0xffffu); a[5] += ds * bf2f(r.z >> 16);
        a[6] += ds * bf2f(r.w & 0xffffu); a[7] += ds * bf2f(r.w >> 16);
        t += 4;
    }
#pragma unroll
    for (int j = 0; j < 8; ++j) {
        a[j] += __shfl_xor(a[j], 16);
        a[j] += __shfl_xor(a[j], 32);
    }
    asum += __shfl_xor(asum, 16);
    asum += __shfl_xor(asum, 32);
    if (q == 0) {
        float d2 = dn * dn;      // t1 = dn * g1: pre-scales the gather2 source
        uint4 st;
        st.x = ((unsigned int)f2bf(a[1] * d2) << 16) | f2bf(a[0] * d2);
        st.y = ((unsigned int)f2bf(a[3] * d2) << 16) | f2bf(a[2] * d2);
        st.z = ((unsigned int)f2bf(a[5] * d2) << 16) | f2bf(a[4] * d2);
        st.w = ((unsigned int)f2bf(a[7] * d2) << 16) | f2bf(a[6] * d2);
        *(uint4*)(yout + (size_t)node * 128 + l16 * 8) = st;
        if (l16 == 0) avec[node] = dn * (asum + dn);   // a = G*1
    }
}

// ---------------- gather2: g2 = bf16(dn * sum t1[nbr]) (sources pre-scaled in t1) ----------------
__global__ __launch_bounds__(256) void k_gather2(
    const unsigned short* __restrict__ tab, const int* __restrict__ cnt,
    const int* __restrict__ csr48, unsigned short* __restrict__ yout) {
    int node = blockIdx.x * 4 + (threadIdx.x >> 6);
    int lane = threadIdx.x & 63;
    int q = lane >> 4, l16 = lane & 15;
    int deg = __builtin_amdgcn_readfirstlane(cnt[node]);
    float dn = rsqrtf((float)(deg + 1));
    if (deg > SLOTS) deg = SLOTS;
    float a[8] = {0.f, 0.f, 0.f, 0.f, 0.f, 0.f, 0.f, 0.f};
    if (q == 0) {  // self term
        uint4 p = *(const uint4*)(tab + (size_t)node * 128 + l16 * 8);
        a[0] = bf2f(p.x & 0xffffu); a[1] = bf2f(p.x >> 16);
        a[2] = bf2f(p.y & 0xffffu); a[3] = bf2f(p.y >> 16);
        a[4] = bf2f(p.z & 0xffffu); a[5] = bf2f(p.z >> 16);
        a[6] = bf2f(p.w & 0xffffu); a[7] = bf2f(p.w >> 16);
    }
    int base = node * SLOTS;
    int t = q;
    while (t + 4 < deg) {
        int s0 = csr48[base + t];
        int s1 = csr48[base + t + 4];
        uint4 r0 = *(const uint4*)(tab + (size_t)s0 * 128 + l16 * 8);
        uint4 r1 = *(const uint4*)(tab + (size_t)s1 * 128 + l16 * 8);
        a[0] += bf2f(r0.x & 0xffffu) + bf2f(r1.x & 0xffffu);
        a[1] += bf2f(r0.x >> 16)     + bf2f(r1.x >> 16);
        a[2] += bf2f(r0.y & 0xffffu) + bf2f(r1.y & 0xffffu);
        a[3] += bf2f(r0.y >> 16)     + bf2f(r1.y >> 16);
        a[4] += bf2f(r0.z & 0xffffu) + bf2f(r1.z & 0xffffu);
        a[5] += bf2f(r0.z >> 16)     + bf2f(r1.z >> 16);
        a[6] += bf2f(r0.w & 0xffffu) + bf2f(r1.w & 0xffffu);
        a[7] += bf2f(r0.w >> 16)     + bf2f(r1.w >> 16);
        t += 8;
    }
    while (t < deg) {
        int s = csr48[base + t];
        uint4 r = *(const uint4*)(tab + (size_t)s * 128 + l16 * 8);
        a[0] += bf2f(r.x & 0xffffu); a[1] += bf2f(r.x >> 16);
        a[2] += bf2f(r.y & 0xffffu); a[3] += bf2f(r.y >> 16);
        a[4] += bf2f(r.z & 0xffffu); a[5] += bf2f(r.z >> 16);
        a[6] += bf2f(r.w & 0xffffu); a[7] += bf2f(r.w >> 16);
        t += 4;
    }
#pragma unroll
    for (int j = 0; j < 8; ++j) {
        a[j] += __shfl_xor(a[j], 16);
        a[j] += __shfl_xor(a[j], 32);
    }
    if (q == 0) {
        uint4 st;
        st.x = ((unsigned int)f2bf(a[1] * dn) << 16) | f2bf(a[0] * dn);
        st.y = ((unsigned int)f2bf(a[3] * dn) << 16) | f2bf(a[2] * dn);
        st.z = ((unsigned int)f2bf(a[5] * dn) << 16) | f2bf(a[4] * dn);
        st.w = ((unsigned int)f2bf(a[7] * dn) << 16) | f2bf(a[6] * dn);
        *(uint4*)(yout + (size_t)node * 128 + l16 * 8) = st;
    }
}

// ---- gemmC + epilogue: [mu|ls] = g2 @ W2c + a (x) bw + [bmu|bls]; out = mu + init*exp(ls) ----
__global__ __launch_bounds__(256) void k_gemmC(
    const unsigned short* __restrict__ g2,   // [NN][128] bf16
    const unsigned short* __restrict__ Bt,   // W2c [128][128] bf16 (n-major, k-contig)
    const float* __restrict__ bw,            // [128] f32 (b1 @ [Wmu|Wls])
    const float* __restrict__ avec,          // [NN] f32
    const float* __restrict__ bmu,
    const float* __restrict__ bls,
    const float* __restrict__ init,
    float* __restrict__ outp,
    int nrows) {
    __shared__ __align__(16) unsigned short As[64 * 136];
    int tid = threadIdx.x;
    int r0 = blockIdx.x * 64;
    for (int c = tid; c < 1024; c += 256) {
        int row = c >> 4, kc = (c & 15) << 3;
        int gr = r0 + row;
        short8 v = {0, 0, 0, 0, 0, 0, 0, 0};
        if (gr < nrows) v = *(const short8*)(g2 + (size_t)gr * 128 + kc);
        *(short8*)(As + row * 136 + kc) = v;
    }
    __syncthreads();
    int lane = tid & 63, wave = tid >> 6;
    int quad = lane >> 4, l16 = lane & 15;
    int cm = wave * 16 + l16;        // mu col (0..63)
    int cl = 64 + cm;                // matching ls col
    float4v acc[4][2];
#pragma unroll
    for (int rt = 0; rt < 4; ++rt) {
        float4v z = {0.f, 0.f, 0.f, 0.f};
        acc[rt][0] = z; acc[rt][1] = z;
    }
#pragma unroll
    for (int ks = 0; ks < 4; ++ks) {
        short8 b0 = *(const short8*)(Bt + (size_t)cm * 128 + ks * 32 + quad * 8);
        short8 b1 = *(const short8*)(Bt + (size_t)cl * 128 + ks * 32 + quad * 8);
        short8 af[4];
#pragma unroll
        for (int rt = 0; rt < 4; ++rt)
            af[rt] = *(const short8*)(As + (rt * 16 + l16) * 136 + ks * 32 + quad * 8);
#pragma unroll
        for (int rt = 0; rt < 4; ++rt) {
            acc[rt][0] = __builtin_amdgcn_mfma_f32_16x16x32_bf16(af[rt], b0, acc[rt][0], 0, 0, 0);
            acc[rt][1] = __builtin_amdgcn_mfma_f32_16x16x32_bf16(af[rt], b1, acc[rt][1], 0, 0, 0);
        }
    }
    float bc_mu = bmu[cm], bc_ls = bls[cm];
    float bwm = bw[cm], bwl = bw[cl];
#pragma unroll
    for (int rt = 0; rt < 4; ++rt)
#pragma unroll
        for (int reg = 0; reg < 4; ++reg) {
            int gr = r0 + rt * 16 + quad * 4 + reg;
            if (gr < nrows) {
                float av = avec[gr];
                float mu = acc[rt][0][reg] + av * bwm + bc_mu;
                float ls = acc[rt][1][reg] + av * bwl + bc_ls;
                float idv = init[(size_t)gr * 64 + cm];
                outp[(size_t)gr * 64 + cm] = mu + idv * expf(ls);
            }
        }
}

extern "C" void kernel_launch(void* const* d_in, const int* in_sizes, int n_in,
                              void* d_out, int out_size, void* d_ws, size_t ws_size,
                              hipStream_t stream) {
    const float* x   = (const float*)d_in[0];  // [N,128] f32
    const int*   ei  = (const int*)d_in[1];    // [2,E] int32
    const float* ind = (const float*)d_in[2];  // [N,64] f32
    const float* W1  = (const float*)d_in[3];  // [128,128] f32
    const float* b1  = (const float*)d_in[4];  // [128] f32
    const float* Wmu = (const float*)d_in[5];  // [128,64] f32
    const float* bmu = (const float*)d_in[6];  // [64] f32
    const float* Wls = (const float*)d_in[7];  // [128,64] f32
    const float* bls = (const float*)d_in[8];  // [64] f32
    float* outp = (float*)d_out;               // [N,64] f32

    char* w = (char*)d_ws;
    auto carve = [&](size_t bytes) -> char* {
        char* p = w; w += (bytes + 255) & ~(size_t)255; return p;
    };
    int*   cnt  = (int*)carve((size_t)NN * 4);
    float* avec = (float*)carve((size_t)NN * 4);
    float* bw   = (float*)carve(128 * 4);
    unsigned short* W2c = (unsigned short*)carve(128 * 128 * 2);
    unsigned short* xs  = (unsigned short*)carve((size_t)NN * 128 * 2);  // xq, then g2 (aliased)
    unsigned short* t1  = (unsigned short*)carve((size_t)NN * 128 * 2);  // gather1 output
    int* csr = (int*)carve((size_t)NN * SLOTS * 4);
    // ~71.5 MB total — proven-fit layout

    hipMemsetAsync(cnt, 0, (size_t)NN * 4, stream);
    k_front<<<FRONT_B, 256, 0, stream>>>(ei, cnt, csr, x, xs, W1, Wmu, Wls, b1, W2c, bw);
    k_gather1<<<NN / 4, 256, 0, stream>>>(xs, cnt, csr, t1, avec);
    k_gather2<<<NN / 4, 256, 0, stream>>>(t1, cnt, csr, xs);            // g2 -> xs buffer
    k_gemmC<<<(NN + 63) / 64, 256, 0, stream>>>(xs, W2c, bw, avec, bmu, bls, ind, outp, NN);
}